// Round 16
// baseline (196.426 us; speedup 1.0000x reference)
//
#include <hip/hip_runtime.h>

typedef int   i32x4v __attribute__((ext_vector_type(4)));
typedef int   i32x8v __attribute__((ext_vector_type(8)));
typedef float f32x16 __attribute__((ext_vector_type(16)));

#define GLOBAL_AS(p) ((const __attribute__((address_space(1))) void*)(p))
#define LDS_AS(p)    ((__attribute__((address_space(3))) void*)(p))
#define BAR()     __builtin_amdgcn_s_barrier()
#define VMCNT(n)  asm volatile("s_waitcnt vmcnt(" #n ")" ::: "memory")

// e2m1 RTN code (values {0,.5,1,1.5,2,3,4,6}; code == bit pattern, sign=0)
__device__ inline int fp4_code(float v) {
  return (v > 0.25f) + (v > 0.75f) + (v > 1.25f) + (v > 1.75f) +
         (v > 2.5f) + (v > 3.5f) + (v > 5.0f);
}

// ---- exp(x) -> fp4 e2m1 nibble-packed [M][K/2] + E8M0 scales (packed layout) ----
// SAt packed: addr = kb*M + (m>>7)*128 + (m&31)*4 + ((m>>5)&3)
__global__ void expcvt_a4_kernel(const float* __restrict__ x,
                                 unsigned char* __restrict__ A4,
                                 unsigned char* __restrict__ SAt,
                                 int M, int K) {
  const int NKB = K >> 5;
  const int t = blockIdx.x * blockDim.x + threadIdx.x;
  const int m = t / NKB, kb = t - m * NKB;
  if (m >= M) return;
  const float4* xs4 = (const float4*)(x + (size_t)m * K + kb * 32);
  float a[32];
  float bm = -3.0e38f;
#pragma unroll
  for (int j = 0; j < 8; ++j) {
    float4 v = xs4[j];
    a[4 * j] = v.x; a[4 * j + 1] = v.y; a[4 * j + 2] = v.z; a[4 * j + 3] = v.w;
    bm = fmaxf(bm, fmaxf(fmaxf(v.x, v.y), fmaxf(v.z, v.w)));
  }
  int e = (int)ceilf(bm * 1.44269504f - 2.58496250f);
  e = min(127, max(-126, e));
  SAt[(size_t)kb * M + ((m >> 7) << 7) + ((m & 31) << 2) + ((m >> 5) & 3)] =
      (unsigned char)(e + 127);
  uint4 u;
  unsigned d[4];
#pragma unroll
  for (int g = 0; g < 4; ++g) {
    unsigned acc = 0;
#pragma unroll
    for (int j = 0; j < 8; ++j) {
      float v = exp2f(a[g * 8 + j] * 1.44269504f - (float)e);
      acc |= (unsigned)fp4_code(v) << (4 * j);
    }
    d[g] = acc;
  }
  u.x = d[0]; u.y = d[1]; u.z = d[2]; u.w = d[3];
  *(uint4*)(A4 + (size_t)m * (K >> 1) + kb * 16) = u;
}

// ---- exp(w) -> fp4, transposed Bt4[n][K/2] + packed scales ----
// SBt packed for 128-wide N blocks: addr = kb*O + (n>>7)*128 + (n&31)*4 + ((n>>5)&3)
__global__ void expcvt_wt4_kernel(const float* __restrict__ w,
                                  unsigned char* __restrict__ Bt4,
                                  unsigned char* __restrict__ SBt,
                                  int D, int O) {
  __shared__ float tile[32][33];
  int c0 = blockIdx.x * 32;   // O (col of w -> n)
  int r0 = blockIdx.y * 32;   // D (row of w -> k); one tile = one 32-K block
  int tx = threadIdx.x;       // 0..31
  int ty = threadIdx.y;       // 0..7
#pragma unroll
  for (int j = 0; j < 4; ++j) {
    int r = r0 + ty + j * 8;
    tile[ty + j * 8][tx] = __expf(w[(size_t)r * O + c0 + tx]);
  }
  __syncthreads();
  if (ty == 0) {
    const int n = c0 + tx;
    float bm = 0.0f;
#pragma unroll
    for (int d = 0; d < 32; ++d) bm = fmaxf(bm, tile[d][tx]);
    int e = (int)ceilf(__log2f(bm) - 2.58496250f);
    e = min(127, max(-126, e));
    SBt[(size_t)(r0 >> 5) * O + ((n >> 7) << 7) + ((n & 31) << 2) +
        ((n >> 5) & 3)] = (unsigned char)(e + 127);
    const float inv = exp2f(-(float)e);
    uint4 u;
    unsigned d4[4];
#pragma unroll
    for (int g = 0; g < 4; ++g) {
      unsigned acc = 0;
#pragma unroll
      for (int j = 0; j < 8; ++j)
        acc |= (unsigned)fp4_code(tile[g * 8 + j][tx] * inv) << (4 * j);
      d4[g] = acc;
    }
    u.x = d4[0]; u.y = d4[1]; u.z = d4[2]; u.w = d4[3];
    *(uint4*)(Bt4 + (size_t)n * (D >> 1) + (r0 >> 1)) = u;
  }
}

// --- 128x128 2-buffer MX-fp4 GEMM, 5 blocks/CU, K-step 128, log+bias epilogue ---
// r13 structure with scales moved LDS -> direct global->VGPR:
// buffer = A 8KB + B 8KB = 16384 B; x2 = 32768/block -> 5 blocks/CU (163840 =
// 160 KiB exactly). __launch_bounds__(256,5) caps VGPR at 102 (20 waves/CU).
// Scale words are coalesced 4B loads: packed word SAt[kb*M + brow + l31*4]
// holds the 4 row-group scale bytes (byte = (m>>5)&3), byte-identical to the
// old LDS path; kb = 4t + 2h + lk (lane-split at 32 -> 2 segments/load).
// Ledger/wave/half-iter: 4 gload_lds + 4 scale dwords = 8 vm-ops -> VMCNT(8)
// retires tile t's set while t+1's 8 stay in flight. sigma_q swizzle (0-conflict).

#define MFMA4(MB, NB, AV, BV, SAv, SBv)                                      \
  acc[MB][NB] = __builtin_amdgcn_mfma_scale_f32_32x32x64_f8f6f4(             \
      AV, BV, acc[MB][NB], 4, 4, 0, SAv, 0, SBv);

#define SCALES(T, S0, S1, S2, S3)                                            \
  {                                                                          \
    const int tt = ((T) < NTK) ? (T) : NTK - 1;                              \
    S0 = *(const int*)(pSA + (size_t)(tt * 4) * M);                          \
    S1 = *(const int*)(pSA + (size_t)(tt * 4 + 2) * M);                      \
    S2 = *(const int*)(pSB + (size_t)(tt * 4) * N);                          \
    S3 = *(const int*)(pSB + (size_t)(tt * 4 + 2) * N);                      \
  }

__global__ __launch_bounds__(256, 5) void gemm_mx4g_kernel(
    const unsigned char* __restrict__ A4, const unsigned char* __restrict__ Bt4,
    const unsigned char* __restrict__ SAt, const unsigned char* __restrict__ SBt,
    const float* __restrict__ bias, float* __restrict__ out,
    int M, int N, int K) {
  __shared__ char lds[32768];          // 2 x 16384 (A+B only)

  const int tid = threadIdx.x;
  const int wid = tid >> 6, lane = tid & 63;
  const int wr = wid >> 1, wc = wid & 1;
  const int l31 = lane & 31, lk = lane >> 5;
  const int NTK = K >> 7;              // 128-elem K-steps (16)
  const size_t Kb = (size_t)K >> 1;    // bytes per fp4 row (1024)

  // XCD-aware bijective swizzle (gridDim.x % 8 == 0 here: 2048)
  const int cpx = gridDim.x >> 3;
  const int v   = (blockIdx.x & 7) * cpx + (blockIdx.x >> 3);
  const int nbn = N >> 7;
  const int bm  = v / nbn, bn = v % nbn;
  const int brow = bm << 7, bcol = bn << 7;

  // read offsets: logical granule gl = lk*2 + h at bits 4..5, XOR sigma_q(l31)
  const int swz = ((l31 & 6) << 3) ^ (l31 & 16);
  const int cR0 = (lk << 5) ^ swz;     // h=0 ; h=1 -> cR0 ^ 16

  // staging sources: granule-swapped + inverse-swizzled (koff = tt*64 added)
  const char* gA[2];
  const char* gB[2];
#pragma unroll
  for (int i = 0; i < 2; ++i) {
    const int o = i * 4096 + tid * 16, row = o >> 6;
    const int sg = (((row & 6) << 3) ^ (row & 16)) >> 4;   // 2-bit granule swz
    const int gl = ((o >> 4) & 3) ^ sg;
    const int gs = ((gl & 1) << 1) | (gl >> 1);            // [lk][h] -> [h][lk]
    gA[i] = (const char*)A4 + (size_t)(brow + row) * Kb + (gs << 4);
    gB[i] = (const char*)Bt4 + (size_t)(bcol + row) * Kb + (gs << 4);
  }
  // scale per-lane bases (lk folded in; per (t,h) add (4t+2h)*M or *N)
  const char* pSA = (const char*)SAt + (size_t)lk * M + brow + l31 * 4;
  const char* pSB = (const char*)SBt + (size_t)lk * N + bcol + l31 * 4;

  auto STAGE = [&](int t, char* base) {
    const int tt = (t < NTK) ? t : NTK - 1;    // clamp keeps ledger uniform
    const int koff = tt << 6;
#pragma unroll
    for (int i = 0; i < 2; ++i) {
      __builtin_amdgcn_global_load_lds(GLOBAL_AS(gA[i] + koff),
          LDS_AS(base + i * 4096 + wid * 1024), 16, 0, 0);
      __builtin_amdgcn_global_load_lds(GLOBAL_AS(gB[i] + koff),
          LDS_AS(base + 8192 + i * 4096 + wid * 1024), 16, 0, 0);
    }
  };

  f32x16 acc[2][2];
#pragma unroll
  for (int m = 0; m < 2; ++m)
#pragma unroll
    for (int n = 0; n < 2; ++n) acc[m][n] = (f32x16)0.0f;

  const int shA = wr << 4;     // byte (2wr+mb) -> shift shA + mb*8 (wave-uniform)
  const int shB = wc << 4;

  auto COMPUTE = [&](const char* base, int sa0w, int sa1w, int sb0w, int sb1w) {
    const char* bA = base + wr * 4096;
    const char* bB = base + 8192 + wc * 4096;
#pragma unroll
    for (int h = 0; h < 2; ++h) {
      const int ch = cR0 ^ (h << 4);
      i32x8v a8[2], b8[2];
#pragma unroll
      for (int mb = 0; mb < 2; ++mb) {
        i32x4v f = *(const i32x4v*)(bA + (mb * 32 + l31) * 64 + ch);
        a8[mb] = __builtin_shufflevector(f, f, 0, 1, 2, 3, -1, -1, -1, -1);
      }
#pragma unroll
      for (int nb = 0; nb < 2; ++nb) {
        i32x4v f = *(const i32x4v*)(bB + (nb * 32 + l31) * 64 + ch);
        b8[nb] = __builtin_shufflevector(f, f, 0, 1, 2, 3, -1, -1, -1, -1);
      }
      const int saw = h ? sa1w : sa0w;
      const int sbw = h ? sb1w : sb0w;
      const int sA0 = (saw >> shA) & 0xFF, sA1 = (saw >> (shA + 8)) & 0xFF;
      const int sB0 = (sbw >> shB) & 0xFF, sB1 = (sbw >> (shB + 8)) & 0xFF;
      MFMA4(0, 0, a8[0], b8[0], sA0, sB0)
      MFMA4(1, 0, a8[1], b8[0], sA1, sB0)
      MFMA4(0, 1, a8[0], b8[1], sA0, sB1)
      MFMA4(1, 1, a8[1], b8[1], sA1, sB1)
    }
  };

  char* const L0 = lds;
  char* const L1 = lds + 16384;

  int sE0, sE1, sE2, sE3, sO0, sO1, sO2, sO3;

  STAGE(0, L0);
  SCALES(0, sE0, sE1, sE2, sE3);

  for (int j = 0; j < (NTK >> 1); ++j) {
    // t = 2j: consume L0 + sE; stage/prefetch t+1 -> L1/sO
    STAGE(2 * j + 1, L1);
    SCALES(2 * j + 1, sO0, sO1, sO2, sO3);
    VMCNT(8);          // retire t's 8 vm-ops (issued a full iter ago)
    BAR();
    COMPUTE(L0, sE0, sE1, sE2, sE3);
    BAR();             // all waves done reading L0 before next STAGE overwrites
    // t = 2j+1: consume L1 + sO; stage/prefetch t+2 -> L0/sE
    STAGE(2 * j + 2, L0);
    SCALES(2 * j + 2, sE0, sE1, sE2, sE3);
    VMCNT(8);
    BAR();
    COMPUTE(L1, sO0, sO1, sO2, sO3);
    BAR();
  }

  VMCNT(0);

  // epilogue: out = log(acc) + bias, nontemporal
  // 32x32 C/D layout: col = lane&31, row = (reg&3) + 8*(reg>>2) + 4*(lane>>5)
  const int col0 = bcol + wc * 64 + l31;
  const int row0 = brow + wr * 64 + lk * 4;
  const float bv0 = bias[col0], bv1 = bias[col0 + 32];
#pragma unroll
  for (int mb = 0; mb < 2; ++mb) {
#pragma unroll
    for (int rg = 0; rg < 16; ++rg) {
      const int row = row0 + mb * 32 + (rg & 3) + 8 * (rg >> 2);
      const size_t ro = (size_t)row * N + col0;
      __builtin_nontemporal_store(__logf(acc[mb][0][rg]) + bv0, &out[ro]);
      __builtin_nontemporal_store(__logf(acc[mb][1][rg]) + bv1, &out[ro + 32]);
    }
  }
}

extern "C" void kernel_launch(void* const* d_in, const int* in_sizes, int n_in,
                              void* d_out, int out_size, void* d_ws, size_t ws_size,
                              hipStream_t stream) {
  const float* inputs = (const float*)d_in[0];
  const float* w      = (const float*)d_in[1];
  const float* bias   = (const float*)d_in[2];
  float* out = (float*)d_out;

  const int O = in_sizes[2];                 // 2048
  const int D = in_sizes[1] / O;             // 2048
  const size_t MD = (size_t)in_sizes[0];     // M*D
  const int M = (int)(MD / (size_t)D);       // 16384

  unsigned char* ws  = (unsigned char*)d_ws;
  unsigned char* A4  = ws;                                   // 16 MB
  unsigned char* Bt4 = ws + MD / 2;                          // 2 MB
  unsigned char* SAt = Bt4 + (size_t)O * D / 2;              // 1 MB
  unsigned char* SBt = SAt + MD / 32;                        // 128 KB

  const int nthr = (int)((MD / 32 + 255) / 256);
  expcvt_a4_kernel<<<nthr, 256, 0, stream>>>(inputs, A4, SAt, M, D);

  dim3 tg(O / 32, D / 32);
  expcvt_wt4_kernel<<<tg, dim3(32, 8), 0, stream>>>(w, Bt4, SBt, D, O);

  dim3 grid((M / 128) * (O / 128));
  gemm_mx4g_kernel<<<grid, 256, 0, stream>>>(A4, Bt4, SAt, SBt, bias, out,
                                             M, O, D);
}

// Round 17
// 90.671 us; speedup vs baseline: 2.1664x; 2.1664x over previous
//
#include <hip/hip_runtime.h>

typedef int   i32x4v __attribute__((ext_vector_type(4)));
typedef int   i32x8v __attribute__((ext_vector_type(8)));
typedef float f32x16 __attribute__((ext_vector_type(16)));

#define GLOBAL_AS(p) ((const __attribute__((address_space(1))) void*)(p))
#define LDS_AS(p)    ((__attribute__((address_space(3))) void*)(p))
#define BAR()     __builtin_amdgcn_s_barrier()
#define VMCNT(n)  asm volatile("s_waitcnt vmcnt(" #n ")" ::: "memory")

// e2m1 RTN code (values {0,.5,1,1.5,2,3,4,6}; code == bit pattern, sign=0)
__device__ inline int fp4_code(float v) {
  return (v > 0.25f) + (v > 0.75f) + (v > 1.25f) + (v > 1.75f) +
         (v > 2.5f) + (v > 3.5f) + (v > 5.0f);
}

// ---- exp(x) -> fp4 e2m1 nibble-packed [M][K/2] + E8M0 scales (packed layout) ----
// SAt packed: addr = kb*M + (m>>7)*128 + (m&31)*4 + ((m>>5)&3)
__global__ void expcvt_a4_kernel(const float* __restrict__ x,
                                 unsigned char* __restrict__ A4,
                                 unsigned char* __restrict__ SAt,
                                 int M, int K) {
  const int NKB = K >> 5;
  const int t = blockIdx.x * blockDim.x + threadIdx.x;
  const int m = t / NKB, kb = t - m * NKB;
  if (m >= M) return;
  const float4* xs4 = (const float4*)(x + (size_t)m * K + kb * 32);
  float a[32];
  float bm = -3.0e38f;
#pragma unroll
  for (int j = 0; j < 8; ++j) {
    float4 v = xs4[j];
    a[4 * j] = v.x; a[4 * j + 1] = v.y; a[4 * j + 2] = v.z; a[4 * j + 3] = v.w;
    bm = fmaxf(bm, fmaxf(fmaxf(v.x, v.y), fmaxf(v.z, v.w)));
  }
  int e = (int)ceilf(bm * 1.44269504f - 2.58496250f);
  e = min(127, max(-126, e));
  SAt[(size_t)kb * M + ((m >> 7) << 7) + ((m & 31) << 2) + ((m >> 5) & 3)] =
      (unsigned char)(e + 127);
  uint4 u;
  unsigned d[4];
#pragma unroll
  for (int g = 0; g < 4; ++g) {
    unsigned acc = 0;
#pragma unroll
    for (int j = 0; j < 8; ++j) {
      float v = exp2f(a[g * 8 + j] * 1.44269504f - (float)e);
      acc |= (unsigned)fp4_code(v) << (4 * j);
    }
    d[g] = acc;
  }
  u.x = d[0]; u.y = d[1]; u.z = d[2]; u.w = d[3];
  *(uint4*)(A4 + (size_t)m * (K >> 1) + kb * 16) = u;
}

// ---- exp(w) -> fp4, transposed Bt4[n][K/2] + packed scales ----
// SBt packed for 128-wide N blocks: addr = kb*O + (n>>7)*128 + (n&31)*4 + ((n>>5)&3)
__global__ void expcvt_wt4_kernel(const float* __restrict__ w,
                                  unsigned char* __restrict__ Bt4,
                                  unsigned char* __restrict__ SBt,
                                  int D, int O) {
  __shared__ float tile[32][33];
  int c0 = blockIdx.x * 32;   // O (col of w -> n)
  int r0 = blockIdx.y * 32;   // D (row of w -> k); one tile = one 32-K block
  int tx = threadIdx.x;       // 0..31
  int ty = threadIdx.y;       // 0..7
#pragma unroll
  for (int j = 0; j < 4; ++j) {
    int r = r0 + ty + j * 8;
    tile[ty + j * 8][tx] = __expf(w[(size_t)r * O + c0 + tx]);
  }
  __syncthreads();
  if (ty == 0) {
    const int n = c0 + tx;
    float bm = 0.0f;
#pragma unroll
    for (int d = 0; d < 32; ++d) bm = fmaxf(bm, tile[d][tx]);
    int e = (int)ceilf(__log2f(bm) - 2.58496250f);
    e = min(127, max(-126, e));
    SBt[(size_t)(r0 >> 5) * O + ((n >> 7) << 7) + ((n & 31) << 2) +
        ((n >> 5) & 3)] = (unsigned char)(e + 127);
    const float inv = exp2f(-(float)e);
    uint4 u;
    unsigned d4[4];
#pragma unroll
    for (int g = 0; g < 4; ++g) {
      unsigned acc = 0;
#pragma unroll
      for (int j = 0; j < 8; ++j)
        acc |= (unsigned)fp4_code(tile[g * 8 + j][tx] * inv) << (4 * j);
      d4[g] = acc;
    }
    u.x = d4[0]; u.y = d4[1]; u.z = d4[2]; u.w = d4[3];
    *(uint4*)(Bt4 + (size_t)n * (D >> 1) + (r0 >> 1)) = u;
  }
}

// --- 128x128 2-buffer MX-fp4 GEMM, 4 blocks/CU, K-step 128, log+bias epilogue ---
// r13 structure + scales direct global->VGPR (coalesced 4B words, byte-identical
// to the old LDS path), at __launch_bounds__(256,4) (128-VGPR cap, no spill —
// r16's (256,5) cap of 102 spilled the accumulator: VGPR=48, scratch traffic).
// Buffer = A 8KB + B 8KB = 16384 B; x2 = 32768/block; 4 blocks/CU by VGPR.
// Ledger/wave/half-iter: 4 gload_lds + 4 scale dwords = 8 vm-ops -> VMCNT(8)
// retires tile t's set while t+1's 8 stay in flight. sigma_q swizzle (0-conflict).

#define MFMA4(MB, NB, AV, BV, SAv, SBv)                                      \
  acc[MB][NB] = __builtin_amdgcn_mfma_scale_f32_32x32x64_f8f6f4(             \
      AV, BV, acc[MB][NB], 4, 4, 0, SAv, 0, SBv);

#define SCALES(T, S0, S1, S2, S3)                                            \
  {                                                                          \
    const int tt = ((T) < NTK) ? (T) : NTK - 1;                              \
    S0 = *(const int*)(pSA + (size_t)(tt * 4) * M);                          \
    S1 = *(const int*)(pSA + (size_t)(tt * 4 + 2) * M);                      \
    S2 = *(const int*)(pSB + (size_t)(tt * 4) * N);                          \
    S3 = *(const int*)(pSB + (size_t)(tt * 4 + 2) * N);                      \
  }

__global__ __launch_bounds__(256, 4) void gemm_mx4h_kernel(
    const unsigned char* __restrict__ A4, const unsigned char* __restrict__ Bt4,
    const unsigned char* __restrict__ SAt, const unsigned char* __restrict__ SBt,
    const float* __restrict__ bias, float* __restrict__ out,
    int M, int N, int K) {
  __shared__ char lds[32768];          // 2 x 16384 (A+B only)

  const int tid = threadIdx.x;
  const int wid = tid >> 6, lane = tid & 63;
  const int wr = wid >> 1, wc = wid & 1;
  const int l31 = lane & 31, lk = lane >> 5;
  const int NTK = K >> 7;              // 128-elem K-steps (16)
  const size_t Kb = (size_t)K >> 1;    // bytes per fp4 row (1024)

  // XCD-aware bijective swizzle (gridDim.x % 8 == 0 here: 2048)
  const int cpx = gridDim.x >> 3;
  const int v   = (blockIdx.x & 7) * cpx + (blockIdx.x >> 3);
  const int nbn = N >> 7;
  const int bm  = v / nbn, bn = v % nbn;
  const int brow = bm << 7, bcol = bn << 7;

  // read offsets: logical granule gl = lk*2 + h at bits 4..5, XOR sigma_q(l31)
  const int swz = ((l31 & 6) << 3) ^ (l31 & 16);
  const int cR0 = (lk << 5) ^ swz;     // h=0 ; h=1 -> cR0 ^ 16

  // staging sources: granule-swapped + inverse-swizzled (koff = tt*64 added)
  const char* gA[2];
  const char* gB[2];
#pragma unroll
  for (int i = 0; i < 2; ++i) {
    const int o = i * 4096 + tid * 16, row = o >> 6;
    const int sg = (((row & 6) << 3) ^ (row & 16)) >> 4;   // 2-bit granule swz
    const int gl = ((o >> 4) & 3) ^ sg;
    const int gs = ((gl & 1) << 1) | (gl >> 1);            // [lk][h] -> [h][lk]
    gA[i] = (const char*)A4 + (size_t)(brow + row) * Kb + (gs << 4);
    gB[i] = (const char*)Bt4 + (size_t)(bcol + row) * Kb + (gs << 4);
  }
  // scale per-lane bases (lk folded in; per (t,h) add (4t+2h)*M or *N)
  const char* pSA = (const char*)SAt + (size_t)lk * M + brow + l31 * 4;
  const char* pSB = (const char*)SBt + (size_t)lk * N + bcol + l31 * 4;

  auto STAGE = [&](int t, char* base) {
    const int tt = (t < NTK) ? t : NTK - 1;    // clamp keeps ledger uniform
    const int koff = tt << 6;
#pragma unroll
    for (int i = 0; i < 2; ++i) {
      __builtin_amdgcn_global_load_lds(GLOBAL_AS(gA[i] + koff),
          LDS_AS(base + i * 4096 + wid * 1024), 16, 0, 0);
      __builtin_amdgcn_global_load_lds(GLOBAL_AS(gB[i] + koff),
          LDS_AS(base + 8192 + i * 4096 + wid * 1024), 16, 0, 0);
    }
  };

  f32x16 acc[2][2];
#pragma unroll
  for (int m = 0; m < 2; ++m)
#pragma unroll
    for (int n = 0; n < 2; ++n) acc[m][n] = (f32x16)0.0f;

  const int shA = wr << 4;     // byte (2wr+mb) -> shift shA + mb*8 (wave-uniform)
  const int shB = wc << 4;

  auto COMPUTE = [&](const char* base, int sa0w, int sa1w, int sb0w, int sb1w) {
    const char* bA = base + wr * 4096;
    const char* bB = base + 8192 + wc * 4096;
#pragma unroll
    for (int h = 0; h < 2; ++h) {
      const int ch = cR0 ^ (h << 4);
      i32x8v a8[2], b8[2];
#pragma unroll
      for (int mb = 0; mb < 2; ++mb) {
        i32x4v f = *(const i32x4v*)(bA + (mb * 32 + l31) * 64 + ch);
        a8[mb] = __builtin_shufflevector(f, f, 0, 1, 2, 3, -1, -1, -1, -1);
      }
#pragma unroll
      for (int nb = 0; nb < 2; ++nb) {
        i32x4v f = *(const i32x4v*)(bB + (nb * 32 + l31) * 64 + ch);
        b8[nb] = __builtin_shufflevector(f, f, 0, 1, 2, 3, -1, -1, -1, -1);
      }
      const int saw = h ? sa1w : sa0w;
      const int sbw = h ? sb1w : sb0w;
      const int sA0 = (saw >> shA) & 0xFF, sA1 = (saw >> (shA + 8)) & 0xFF;
      const int sB0 = (sbw >> shB) & 0xFF, sB1 = (sbw >> (shB + 8)) & 0xFF;
      MFMA4(0, 0, a8[0], b8[0], sA0, sB0)
      MFMA4(1, 0, a8[1], b8[0], sA1, sB0)
      MFMA4(0, 1, a8[0], b8[1], sA0, sB1)
      MFMA4(1, 1, a8[1], b8[1], sA1, sB1)
    }
  };

  char* const L0 = lds;
  char* const L1 = lds + 16384;

  int sE0, sE1, sE2, sE3, sO0, sO1, sO2, sO3;

  STAGE(0, L0);
  SCALES(0, sE0, sE1, sE2, sE3);

  for (int j = 0; j < (NTK >> 1); ++j) {
    // t = 2j: consume L0 + sE; stage/prefetch t+1 -> L1/sO
    STAGE(2 * j + 1, L1);
    SCALES(2 * j + 1, sO0, sO1, sO2, sO3);
    VMCNT(8);          // retire t's 8 vm-ops (issued a full iter ago)
    BAR();
    COMPUTE(L0, sE0, sE1, sE2, sE3);
    BAR();             // all waves done reading L0 before next STAGE overwrites
    // t = 2j+1: consume L1 + sO; stage/prefetch t+2 -> L0/sE
    STAGE(2 * j + 2, L0);
    SCALES(2 * j + 2, sE0, sE1, sE2, sE3);
    VMCNT(8);
    BAR();
    COMPUTE(L1, sO0, sO1, sO2, sO3);
    BAR();
  }

  VMCNT(0);

  // epilogue: out = log(acc) + bias, nontemporal
  // 32x32 C/D layout: col = lane&31, row = (reg&3) + 8*(reg>>2) + 4*(lane>>5)
  const int col0 = bcol + wc * 64 + l31;
  const int row0 = brow + wr * 64 + lk * 4;
  const float bv0 = bias[col0], bv1 = bias[col0 + 32];
#pragma unroll
  for (int mb = 0; mb < 2; ++mb) {
#pragma unroll
    for (int rg = 0; rg < 16; ++rg) {
      const int row = row0 + mb * 32 + (rg & 3) + 8 * (rg >> 2);
      const size_t ro = (size_t)row * N + col0;
      __builtin_nontemporal_store(__logf(acc[mb][0][rg]) + bv0, &out[ro]);
      __builtin_nontemporal_store(__logf(acc[mb][1][rg]) + bv1, &out[ro + 32]);
    }
  }
}

extern "C" void kernel_launch(void* const* d_in, const int* in_sizes, int n_in,
                              void* d_out, int out_size, void* d_ws, size_t ws_size,
                              hipStream_t stream) {
  const float* inputs = (const float*)d_in[0];
  const float* w      = (const float*)d_in[1];
  const float* bias   = (const float*)d_in[2];
  float* out = (float*)d_out;

  const int O = in_sizes[2];                 // 2048
  const int D = in_sizes[1] / O;             // 2048
  const size_t MD = (size_t)in_sizes[0];     // M*D
  const int M = (int)(MD / (size_t)D);       // 16384

  unsigned char* ws  = (unsigned char*)d_ws;
  unsigned char* A4  = ws;                                   // 16 MB
  unsigned char* Bt4 = ws + MD / 2;                          // 2 MB
  unsigned char* SAt = Bt4 + (size_t)O * D / 2;              // 1 MB
  unsigned char* SBt = SAt + MD / 32;                        // 128 KB

  const int nthr = (int)((MD / 32 + 255) / 256);
  expcvt_a4_kernel<<<nthr, 256, 0, stream>>>(inputs, A4, SAt, M, D);

  dim3 tg(O / 32, D / 32);
  expcvt_wt4_kernel<<<tg, dim3(32, 8), 0, stream>>>(w, Bt4, SBt, D, O);

  dim3 grid((M / 128) * (O / 128));
  gemm_mx4h_kernel<<<grid, 256, 0, stream>>>(A4, Bt4, SAt, SBt, bias, out,
                                             M, O, D);
}

// Round 18
// 90.199 us; speedup vs baseline: 2.1777x; 1.0052x over previous
//
#include <hip/hip_runtime.h>

typedef int   i32x4v __attribute__((ext_vector_type(4)));
typedef int   i32x8v __attribute__((ext_vector_type(8)));
typedef float f32x16 __attribute__((ext_vector_type(16)));

// e2m1 RTN code (values {0,.5,1,1.5,2,3,4,6}; code == bit pattern, sign=0)
__device__ inline int fp4_code(float v) {
  return (v > 0.25f) + (v > 0.75f) + (v > 1.25f) + (v > 1.75f) +
         (v > 2.5f) + (v > 3.5f) + (v > 5.0f);
}

// panel address: P[blk][t][h][r][32B], 8KB per (blk,t), 4KB per h
__device__ inline size_t panel_addr(int blk, int t, int h, int r, int sub) {
  return ((((size_t)blk * 16 + t) * 2 + h) << 12) + ((size_t)r << 5) + (sub << 4);
}

// ---- exp(x) -> fp4 e2m1, packed into fragment panels Ap + E8M0 scales ----
// SAt packed: addr = kb*M + (m>>7)*128 + (m&31)*4 + ((m>>5)&3)
__global__ void expcvt_a4_kernel(const float* __restrict__ x,
                                 unsigned char* __restrict__ A4,
                                 unsigned char* __restrict__ SAt,
                                 int M, int K) {
  const int NKB = K >> 5;
  const int t = blockIdx.x * blockDim.x + threadIdx.x;
  const int m = t / NKB, kb = t - m * NKB;
  if (m >= M) return;
  const float4* xs4 = (const float4*)(x + (size_t)m * K + kb * 32);
  float a[32];
  float bm = -3.0e38f;
#pragma unroll
  for (int j = 0; j < 8; ++j) {
    float4 v = xs4[j];
    a[4 * j] = v.x; a[4 * j + 1] = v.y; a[4 * j + 2] = v.z; a[4 * j + 3] = v.w;
    bm = fmaxf(bm, fmaxf(fmaxf(v.x, v.y), fmaxf(v.z, v.w)));
  }
  int e = (int)ceilf(bm * 1.44269504f - 2.58496250f);
  e = min(127, max(-126, e));
  SAt[(size_t)kb * M + ((m >> 7) << 7) + ((m & 31) << 2) + ((m >> 5) & 3)] =
      (unsigned char)(e + 127);
  uint4 u;
  unsigned d[4];
#pragma unroll
  for (int g = 0; g < 4; ++g) {
    unsigned acc = 0;
#pragma unroll
    for (int j = 0; j < 8; ++j) {
      float v = exp2f(a[g * 8 + j] * 1.44269504f - (float)e);
      acc |= (unsigned)fp4_code(v) << (4 * j);
    }
    d[g] = acc;
  }
  u.x = d[0]; u.y = d[1]; u.z = d[2]; u.w = d[3];
  *(uint4*)(A4 + panel_addr(m >> 7, kb >> 2, (kb >> 1) & 1, m & 127, kb & 1)) = u;
}

// ---- exp(w) -> fp4, packed into fragment panels Bp + packed scales ----
// SBt packed: addr = kb*O + (n>>7)*128 + (n&31)*4 + ((n>>5)&3)
__global__ void expcvt_wt4_kernel(const float* __restrict__ w,
                                  unsigned char* __restrict__ Bt4,
                                  unsigned char* __restrict__ SBt,
                                  int D, int O) {
  __shared__ float tile[32][33];
  int c0 = blockIdx.x * 32;   // O (col of w -> n)
  int r0 = blockIdx.y * 32;   // D (row of w -> k); one tile = one 32-K block
  int tx = threadIdx.x;       // 0..31
  int ty = threadIdx.y;       // 0..7
#pragma unroll
  for (int j = 0; j < 4; ++j) {
    int r = r0 + ty + j * 8;
    tile[ty + j * 8][tx] = __expf(w[(size_t)r * O + c0 + tx]);
  }
  __syncthreads();
  if (ty == 0) {
    const int n = c0 + tx;
    const int kb = r0 >> 5;
    float bm = 0.0f;
#pragma unroll
    for (int d = 0; d < 32; ++d) bm = fmaxf(bm, tile[d][tx]);
    int e = (int)ceilf(__log2f(bm) - 2.58496250f);
    e = min(127, max(-126, e));
    SBt[(size_t)kb * O + ((n >> 7) << 7) + ((n & 31) << 2) +
        ((n >> 5) & 3)] = (unsigned char)(e + 127);
    const float inv = exp2f(-(float)e);
    uint4 u;
    unsigned d4[4];
#pragma unroll
    for (int g = 0; g < 4; ++g) {
      unsigned acc = 0;
#pragma unroll
      for (int j = 0; j < 8; ++j)
        acc |= (unsigned)fp4_code(tile[g * 8 + j][tx] * inv) << (4 * j);
      d4[g] = acc;
    }
    u.x = d4[0]; u.y = d4[1]; u.z = d4[2]; u.w = d4[3];
    *(uint4*)(Bt4 + panel_addr(n >> 7, kb >> 2, (kb >> 1) & 1, n & 127, kb & 1)) = u;
  }
}

// --- 128x128 MX-fp4 GEMM: NO LDS, NO BARRIERS — pure register streaming ---
// A/B are pre-packed into fragment panels: a wave's operand load is 1KB fully
// contiguous (lanes: r=l31-group, sub=lk). Per t: 8 x dwordx4 + 4 scale dwords
// -> VGPR, double-buffered across the x2 unroll; compiler inserts counted
// waitcnts; waves are fully independent (latency hidden by 12 free waves/CU).
// 256 thr = 4 waves (2M x 2N); wave C-tile 64x64; acc 64 VGPR; ~145 total
// -> __launch_bounds__(256,3) (cap 168, no spill — r16 lesson).

#define PAD8(f) __builtin_shufflevector(f, f, 0, 1, 2, 3, -1, -1, -1, -1)
#define MFMA4(MB, NB, AV, BV, SAv, SBv)                                      \
  acc[MB][NB] = __builtin_amdgcn_mfma_scale_f32_32x32x64_f8f6f4(             \
      AV, BV, acc[MB][NB], 4, 4, 0, SAv, 0, SBv);

#define LOADT(T, AF, BF, S0, S1, S2, S3)                                     \
  {                                                                          \
    const int tt = ((T) < NTK) ? (T) : NTK - 1;                              \
    const char* pa = pA + tt * 8192;                                         \
    const char* pb = pB + tt * 8192;                                         \
    AF[0][0] = *(const i32x4v*)(pa);                                         \
    AF[1][0] = *(const i32x4v*)(pa + 1024);                                  \
    AF[0][1] = *(const i32x4v*)(pa + 4096);                                  \
    AF[1][1] = *(const i32x4v*)(pa + 5120);                                  \
    BF[0][0] = *(const i32x4v*)(pb);                                         \
    BF[1][0] = *(const i32x4v*)(pb + 1024);                                  \
    BF[0][1] = *(const i32x4v*)(pb + 4096);                                  \
    BF[1][1] = *(const i32x4v*)(pb + 5120);                                  \
    S0 = *(const int*)(pSA + (size_t)(tt * 4) * M);                          \
    S1 = *(const int*)(pSA + (size_t)(tt * 4 + 2) * M);                      \
    S2 = *(const int*)(pSB + (size_t)(tt * 4) * N);                          \
    S3 = *(const int*)(pSB + (size_t)(tt * 4 + 2) * N);                      \
  }

#define COMPUTE(AF, BF, SA0W, SA1W, SB0W, SB1W)                              \
  _Pragma("unroll") for (int h = 0; h < 2; ++h) {                            \
    const int saw = h ? (SA1W) : (SA0W);                                     \
    const int sbw = h ? (SB1W) : (SB0W);                                     \
    const int sA0 = (saw >> shA) & 0xFF, sA1 = (saw >> (shA + 8)) & 0xFF;    \
    const int sB0 = (sbw >> shB) & 0xFF, sB1 = (sbw >> (shB + 8)) & 0xFF;    \
    MFMA4(0, 0, PAD8(AF[0][h]), PAD8(BF[0][h]), sA0, sB0)                    \
    MFMA4(1, 0, PAD8(AF[1][h]), PAD8(BF[0][h]), sA1, sB0)                    \
    MFMA4(0, 1, PAD8(AF[0][h]), PAD8(BF[1][h]), sA0, sB1)                    \
    MFMA4(1, 1, PAD8(AF[1][h]), PAD8(BF[1][h]), sA1, sB1)                    \
  }

__global__ __launch_bounds__(256, 3) void gemm_mx4s_kernel(
    const unsigned char* __restrict__ Ap, const unsigned char* __restrict__ Bp,
    const unsigned char* __restrict__ SAt, const unsigned char* __restrict__ SBt,
    const float* __restrict__ bias, float* __restrict__ out,
    int M, int N, int K) {
  const int tid = threadIdx.x;
  const int wid = tid >> 6, lane = tid & 63;
  const int wr = wid >> 1, wc = wid & 1;
  const int l31 = lane & 31, lk = lane >> 5;
  const int NTK = K >> 7;              // 128-elem K-steps (16)

  // XCD-aware bijective swizzle (gridDim.x % 8 == 0 here: 2048); same-bm
  // blocks cluster per XCD -> A panels are L2-local, B panels L2-resident.
  const int cpx = gridDim.x >> 3;
  const int v   = (blockIdx.x & 7) * cpx + (blockIdx.x >> 3);
  const int nbn = N >> 7;
  const int bm  = v / nbn, bn = v % nbn;
  const int brow = bm << 7, bcol = bn << 7;

  // per-lane fragment bases: frag(t,mb,h) = pA + t*8192 + h*4096 + mb*1024
  const char* pA = (const char*)Ap + ((size_t)bm << 17) +
                   ((wr * 64 + l31) << 5) + (lk << 4);
  const char* pB = (const char*)Bp + ((size_t)bn << 17) +
                   ((wc * 64 + l31) << 5) + (lk << 4);

  // scale per-lane bases (lk folded in; per (t,h) add (4t+2h)*M or *N)
  const char* pSA = (const char*)SAt + (size_t)lk * M + brow + l31 * 4;
  const char* pSB = (const char*)SBt + (size_t)lk * N + bcol + l31 * 4;

  f32x16 acc[2][2];
#pragma unroll
  for (int m = 0; m < 2; ++m)
#pragma unroll
    for (int n = 0; n < 2; ++n) acc[m][n] = (f32x16)0.0f;

  const int shA = wr << 4;     // byte (2wr+mb) -> shift shA + mb*8 (wave-uniform)
  const int shB = wc << 4;

  i32x4v aE[2][2], bE[2][2], aO[2][2], bO[2][2];
  int sE0, sE1, sE2, sE3, sO0, sO1, sO2, sO3;

  LOADT(0, aE, bE, sE0, sE1, sE2, sE3);

  for (int j = 0; j < (NTK >> 1); ++j) {
    LOADT(2 * j + 1, aO, bO, sO0, sO1, sO2, sO3);   // prefetch t+1
    COMPUTE(aE, bE, sE0, sE1, sE2, sE3);            // consume t
    LOADT(2 * j + 2, aE, bE, sE0, sE1, sE2, sE3);   // prefetch t+2
    COMPUTE(aO, bO, sO0, sO1, sO2, sO3);            // consume t+1
  }

  // epilogue: out = log(acc) + bias, nontemporal
  // 32x32 C/D layout: col = lane&31, row = (reg&3) + 8*(reg>>2) + 4*(lane>>5)
  const int col0 = bcol + wc * 64 + l31;
  const int row0 = brow + wr * 64 + lk * 4;
  const float bv0 = bias[col0], bv1 = bias[col0 + 32];
#pragma unroll
  for (int mb = 0; mb < 2; ++mb) {
#pragma unroll
    for (int rg = 0; rg < 16; ++rg) {
      const int row = row0 + mb * 32 + (rg & 3) + 8 * (rg >> 2);
      const size_t ro = (size_t)row * N + col0;
      __builtin_nontemporal_store(__logf(acc[mb][0][rg]) + bv0, &out[ro]);
      __builtin_nontemporal_store(__logf(acc[mb][1][rg]) + bv1, &out[ro + 32]);
    }
  }
}

extern "C" void kernel_launch(void* const* d_in, const int* in_sizes, int n_in,
                              void* d_out, int out_size, void* d_ws, size_t ws_size,
                              hipStream_t stream) {
  const float* inputs = (const float*)d_in[0];
  const float* w      = (const float*)d_in[1];
  const float* bias   = (const float*)d_in[2];
  float* out = (float*)d_out;

  const int O = in_sizes[2];                 // 2048
  const int D = in_sizes[1] / O;             // 2048
  const size_t MD = (size_t)in_sizes[0];     // M*D
  const int M = (int)(MD / (size_t)D);       // 16384

  unsigned char* ws  = (unsigned char*)d_ws;
  unsigned char* A4  = ws;                                   // 16 MB (panels)
  unsigned char* Bt4 = ws + MD / 2;                          // 2 MB (panels)
  unsigned char* SAt = Bt4 + (size_t)O * D / 2;              // 1 MB
  unsigned char* SBt = SAt + MD / 32;                        // 128 KB

  const int nthr = (int)((MD / 32 + 255) / 256);
  expcvt_a4_kernel<<<nthr, 256, 0, stream>>>(inputs, A4, SAt, M, D);

  dim3 tg(O / 32, D / 32);
  expcvt_wt4_kernel<<<tg, dim3(32, 8), 0, stream>>>(w, Bt4, SBt, D, O);

  dim3 grid((M / 128) * (O / 128));
  gemm_mx4s_kernel<<<grid, 256, 0, stream>>>(A4, Bt4, SAt, SBt, bias, out,
                                             M, O, D);
}

// Round 19
// 86.730 us; speedup vs baseline: 2.2648x; 1.0400x over previous
//
#include <hip/hip_runtime.h>

typedef int   i32x4v __attribute__((ext_vector_type(4)));
typedef int   i32x8v __attribute__((ext_vector_type(8)));
typedef float f32x16 __attribute__((ext_vector_type(16)));

#define GLOBAL_AS(p) ((const __attribute__((address_space(1))) void*)(p))
#define LDS_AS(p)    ((__attribute__((address_space(3))) void*)(p))
#define BAR()     __builtin_amdgcn_s_barrier()
#define VMCNT(n)  asm volatile("s_waitcnt vmcnt(" #n ")" ::: "memory")

// e2m1 RTN code (values {0,.5,1,1.5,2,3,4,6}; code == bit pattern, sign=0)
__device__ inline int fp4_code(float v) {
  return (v > 0.25f) + (v > 0.75f) + (v > 1.25f) + (v > 1.75f) +
         (v > 2.5f) + (v > 3.5f) + (v > 5.0f);
}

// ---- fused conversion: blocks [0,nA) convert inputs, blocks [nA,..) convert w ----
// A4 : [M][K/2] fp4 nibble-packed; SAt packed: kb*M + (m>>7)*128 + (m&31)*4 + ((m>>5)&3)
// Bt4: [N][D/2] fp4 transposed;    SBt packed: kb*O + (n>>7)*128 + (n&31)*4 + ((n>>5)&3)
__global__ void expcvt_fused_kernel(const float* __restrict__ x,
                                    const float* __restrict__ w,
                                    unsigned char* __restrict__ A4,
                                    unsigned char* __restrict__ SAt,
                                    unsigned char* __restrict__ Bt4,
                                    unsigned char* __restrict__ SBt,
                                    int M, int K, int D, int O, int nA) {
  __shared__ float tile[32][33];

  if ((int)blockIdx.x < nA) {
    // ---------------- A part: one thread per (row m, 32-elem K-block kb) ----------------
    const int NKB = K >> 5;
    const int t = blockIdx.x * blockDim.x + threadIdx.x;
    const int m = t / NKB, kb = t - m * NKB;
    if (m >= M) return;
    const float4* xs4 = (const float4*)(x + (size_t)m * K + kb * 32);
    float a[32];
    float bm = -3.0e38f;
#pragma unroll
    for (int j = 0; j < 8; ++j) {
      float4 v = xs4[j];
      a[4 * j] = v.x; a[4 * j + 1] = v.y; a[4 * j + 2] = v.z; a[4 * j + 3] = v.w;
      bm = fmaxf(bm, fmaxf(fmaxf(v.x, v.y), fmaxf(v.z, v.w)));
    }
    int e = (int)ceilf(bm * 1.44269504f - 2.58496250f);
    e = min(127, max(-126, e));
    SAt[(size_t)kb * M + ((m >> 7) << 7) + ((m & 31) << 2) + ((m >> 5) & 3)] =
        (unsigned char)(e + 127);
    uint4 u;
    unsigned d[4];
#pragma unroll
    for (int g = 0; g < 4; ++g) {
      unsigned acc = 0;
#pragma unroll
      for (int j = 0; j < 8; ++j) {
        float v = exp2f(a[g * 8 + j] * 1.44269504f - (float)e);
        acc |= (unsigned)fp4_code(v) << (4 * j);
      }
      d[g] = acc;
    }
    u.x = d[0]; u.y = d[1]; u.z = d[2]; u.w = d[3];
    *(uint4*)(A4 + (size_t)m * (K >> 1) + kb * 16) = u;
  } else {
    // ---------------- W part: 32x32 tile transpose + quantize ----------------
    const int b2 = (int)blockIdx.x - nA;
    const int nbx = O >> 5;
    const int c0 = (b2 % nbx) * 32;   // O (col of w -> n)
    const int r0 = (b2 / nbx) * 32;   // D (row of w -> k); one tile = one 32-K block
    const int tx = threadIdx.x & 31;
    const int ty = threadIdx.x >> 5;  // 0..7
#pragma unroll
    for (int j = 0; j < 4; ++j) {
      int r = r0 + ty + j * 8;
      tile[ty + j * 8][tx] = __expf(w[(size_t)r * O + c0 + tx]);
    }
    __syncthreads();
    if (ty == 0) {
      const int n = c0 + tx;
      float bm = 0.0f;
#pragma unroll
      for (int dd = 0; dd < 32; ++dd) bm = fmaxf(bm, tile[dd][tx]);
      int e = (int)ceilf(__log2f(bm) - 2.58496250f);
      e = min(127, max(-126, e));
      SBt[(size_t)(r0 >> 5) * O + ((n >> 7) << 7) + ((n & 31) << 2) +
          ((n >> 5) & 3)] = (unsigned char)(e + 127);
      const float inv = exp2f(-(float)e);
      uint4 u;
      unsigned d4[4];
#pragma unroll
      for (int g = 0; g < 4; ++g) {
        unsigned acc = 0;
#pragma unroll
        for (int j = 0; j < 8; ++j)
          acc |= (unsigned)fp4_code(tile[g * 8 + j][tx] * inv) << (4 * j);
        d4[g] = acc;
      }
      u.x = d4[0]; u.y = d4[1]; u.z = d4[2]; u.w = d4[3];
      *(uint4*)(Bt4 + (size_t)n * (D >> 1) + (r0 >> 1)) = u;
    }
  }
}

// --- 128x128 2-buffer MX-fp4 GEMM, 4 blocks/CU, K-step 128, log+bias epilogue ---
// r13 structure verbatim (best measured: 88.8 us total).
// 256 thr = 4 waves (2M x 2N); wave C-tile 64x64 = 2mb x 2nb of 32x32x64; acc 64
// VGPR -> ~100 regs/wave -> 4 waves/SIMD. Buffer 17408B: A 8KB @0, B 8KB @8192,
// SA 512B @16384, SB 512B @16896; x2 = 34816 -> 4 blocks/CU (16 waves).
// Double-buffer, stage distance 1 iter: per half { STAGE(t+1 -> other buf);
// VMCNT(5) retires t's loads; BAR; COMPUTE(buf t); BAR }. sigma_q swizzle
// (proven 0-conflict).

#define MFMA4(MB, NB, AV, BV, SAv, SBv)                                      \
  acc[MB][NB] = __builtin_amdgcn_mfma_scale_f32_32x32x64_f8f6f4(             \
      AV, BV, acc[MB][NB], 4, 4, 0, SAv, 0, SBv);

__global__ __launch_bounds__(256, 4) void gemm_mx4d_kernel(
    const unsigned char* __restrict__ A4, const unsigned char* __restrict__ Bt4,
    const unsigned char* __restrict__ SAt, const unsigned char* __restrict__ SBt,
    const float* __restrict__ bias, float* __restrict__ out,
    int M, int N, int K) {
  __shared__ char lds[34816];          // 2 x 17408

  const int tid = threadIdx.x;
  const int wid = tid >> 6, lane = tid & 63;
  const int wr = wid >> 1, wc = wid & 1;
  const int l31 = lane & 31, lk = lane >> 5;
  const int NTK = K >> 7;              // 128-elem K-steps (16)
  const size_t Kb = (size_t)K >> 1;    // bytes per fp4 row (1024)

  // XCD-aware bijective swizzle (gridDim.x % 8 == 0 here: 2048)
  const int cpx = gridDim.x >> 3;
  const int v   = (blockIdx.x & 7) * cpx + (blockIdx.x >> 3);
  const int nbn = N >> 7;
  const int bm  = v / nbn, bn = v % nbn;
  const int brow = bm << 7, bcol = bn << 7;

  // read offsets: logical granule gl = lk*2 + h at bits 4..5, XOR sigma_q(l31)
  const int swz = ((l31 & 6) << 3) ^ (l31 & 16);
  const int cR0 = (lk << 5) ^ swz;     // h=0 ; h=1 -> cR0 ^ 16

  // staging sources: granule-swapped + inverse-swizzled (koff = tt*64 added)
  const char* gA[2];
  const char* gB[2];
#pragma unroll
  for (int i = 0; i < 2; ++i) {
    const int o = i * 4096 + tid * 16, row = o >> 6;
    const int sg = (((row & 6) << 3) ^ (row & 16)) >> 4;   // 2-bit granule swz
    const int gl = ((o >> 4) & 3) ^ sg;
    const int gs = ((gl & 1) << 1) | (gl >> 1);            // [lk][h] -> [h][lk]
    gA[i] = (const char*)A4 + (size_t)(brow + row) * Kb + (gs << 4);
    gB[i] = (const char*)Bt4 + (size_t)(bcol + row) * Kb + (gs << 4);
  }
  // scale source: waves 0/1 -> SA kb {0,1}/{2,3}; waves 2/3 -> SB kb {0,1}/{2,3}
  const char* gS;
  size_t sstep;
  if (wid < 2) {
    gS = (const char*)SAt + ((size_t)(lane >> 5) + 2 * wid) * M + brow + l31 * 4;
    sstep = 4 * (size_t)M;
  } else {
    gS = (const char*)SBt + ((size_t)(lane >> 5) + 2 * (wid - 2)) * N + bcol +
         l31 * 4;
    sstep = 4 * (size_t)N;
  }

  auto STAGE = [&](int t, char* base) {
    const int tt = (t < NTK) ? t : NTK - 1;    // clamp keeps ledger uniform
    const int koff = tt << 6;
#pragma unroll
    for (int i = 0; i < 2; ++i) {
      __builtin_amdgcn_global_load_lds(GLOBAL_AS(gA[i] + koff),
          LDS_AS(base + i * 4096 + wid * 1024), 16, 0, 0);
      __builtin_amdgcn_global_load_lds(GLOBAL_AS(gB[i] + koff),
          LDS_AS(base + 8192 + i * 4096 + wid * 1024), 16, 0, 0);
    }
    __builtin_amdgcn_global_load_lds(GLOBAL_AS(gS + (size_t)tt * sstep),
        LDS_AS(base + 16384 + wid * 256 + lane * 4), 4, 0, 0);
  };

  f32x16 acc[2][2];
#pragma unroll
  for (int m = 0; m < 2; ++m)
#pragma unroll
    for (int n = 0; n < 2; ++n) acc[m][n] = (f32x16)0.0f;

  const int shA = wr << 4;     // byte (2wr+mb) -> shift shA + mb*8 (wave-uniform)
  const int shB = wc << 4;

  auto COMPUTE = [&](const char* base) {
    const char* bA = base + wr * 4096;
    const char* bB = base + 8192 + wc * 4096;
#pragma unroll
    for (int h = 0; h < 2; ++h) {
      const int ch = cR0 ^ (h << 4);
      i32x8v a8[2], b8[2];
#pragma unroll
      for (int mb = 0; mb < 2; ++mb) {
        i32x4v f = *(const i32x4v*)(bA + (mb * 32 + l31) * 64 + ch);
        a8[mb] = __builtin_shufflevector(f, f, 0, 1, 2, 3, -1, -1, -1, -1);
      }
#pragma unroll
      for (int nb = 0; nb < 2; ++nb) {
        i32x4v f = *(const i32x4v*)(bB + (nb * 32 + l31) * 64 + ch);
        b8[nb] = __builtin_shufflevector(f, f, 0, 1, 2, 3, -1, -1, -1, -1);
      }
      const int kb2 = 2 * h + lk;
      const int saw = *(const int*)(base + 16384 + kb2 * 128 + l31 * 4);
      const int sbw = *(const int*)(base + 16896 + kb2 * 128 + l31 * 4);
      const int sA0 = (saw >> shA) & 0xFF, sA1 = (saw >> (shA + 8)) & 0xFF;
      const int sB0 = (sbw >> shB) & 0xFF, sB1 = (sbw >> (shB + 8)) & 0xFF;
      MFMA4(0, 0, a8[0], b8[0], sA0, sB0)
      MFMA4(1, 0, a8[1], b8[0], sA1, sB0)
      MFMA4(0, 1, a8[0], b8[1], sA0, sB1)
      MFMA4(1, 1, a8[1], b8[1], sA1, sB1)
    }
  };

  char* const L0 = lds;
  char* const L1 = lds + 17408;

  STAGE(0, L0);

  for (int j = 0; j < (NTK >> 1); ++j) {
    // t = 2j: consume L0, stage t+1 -> L1
    STAGE(2 * j + 1, L1);
    VMCNT(5);          // retire t's 5 loads (issued a full iter ago)
    BAR();
    COMPUTE(L0);
    BAR();             // all waves done reading L0 before next STAGE overwrites
    // t = 2j+1: consume L1, stage t+2 -> L0
    STAGE(2 * j + 2, L0);
    VMCNT(5);
    BAR();
    COMPUTE(L1);
    BAR();
  }

  VMCNT(0);

  // epilogue: out = log(acc) + bias, nontemporal
  // 32x32 C/D layout: col = lane&31, row = (reg&3) + 8*(reg>>2) + 4*(lane>>5)
  const int col0 = bcol + wc * 64 + l31;
  const int row0 = brow + wr * 64 + lk * 4;
  const float bv0 = bias[col0], bv1 = bias[col0 + 32];
#pragma unroll
  for (int mb = 0; mb < 2; ++mb) {
#pragma unroll
    for (int rg = 0; rg < 16; ++rg) {
      const int row = row0 + mb * 32 + (rg & 3) + 8 * (rg >> 2);
      const size_t ro = (size_t)row * N + col0;
      __builtin_nontemporal_store(__logf(acc[mb][0][rg]) + bv0, &out[ro]);
      __builtin_nontemporal_store(__logf(acc[mb][1][rg]) + bv1, &out[ro + 32]);
    }
  }
}

extern "C" void kernel_launch(void* const* d_in, const int* in_sizes, int n_in,
                              void* d_out, int out_size, void* d_ws, size_t ws_size,
                              hipStream_t stream) {
  const float* inputs = (const float*)d_in[0];
  const float* w      = (const float*)d_in[1];
  const float* bias   = (const float*)d_in[2];
  float* out = (float*)d_out;

  const int O = in_sizes[2];                 // 2048
  const int D = in_sizes[1] / O;             // 2048
  const size_t MD = (size_t)in_sizes[0];     // M*D
  const int M = (int)(MD / (size_t)D);       // 16384

  unsigned char* ws  = (unsigned char*)d_ws;
  unsigned char* A4  = ws;                                   // 16 MB
  unsigned char* Bt4 = ws + MD / 2;                          // 2 MB
  unsigned char* SAt = Bt4 + (size_t)O * D / 2;              // 1 MB
  unsigned char* SBt = SAt + MD / 32;                        // 128 KB

  const int nA = (int)((MD / 32 + 255) / 256);               // A-conversion blocks
  const int nW = (O / 32) * (D / 32);                        // W-conversion blocks
  expcvt_fused_kernel<<<nA + nW, 256, 0, stream>>>(inputs, w, A4, SAt, Bt4, SBt,
                                                   M, D, D, O, nA);

  dim3 grid((M / 128) * (O / 128));
  gemm_mx4d_kernel<<<grid, 256, 0, stream>>>(A4, Bt4, SAt, SBt, bias, out,
                                             M, O, D);
}